// Round 1
// baseline (1086.907 us; speedup 1.0000x reference)
//
#include <hip/hip_runtime.h>

// Problem constants (from the reference)
#define NVIEWS 3
#define NROWS 131072
#define DDIM 512
#define NEG_SLOPE 0.01f

typedef float v4f __attribute__((ext_vector_type(4)));

// One 64-lane wave per row n:
//   - each lane holds 8 floats (2 x float4) of each of the 3 views' row
//   - 3 dot products via per-lane FMA + 6-step shfl_xor butterfly
//   - leaky_relu + 3-way softmax computed redundantly per lane
//   - weighted sum from registers (xs read exactly once from HBM)
__global__ __launch_bounds__(256) void adaptive_fusion_kernel(
    const float* __restrict__ xs,      // [V, N, D]
    const float* __restrict__ alpha_w, // [D]
    const float* __restrict__ alpha_b, // [1]
    float* __restrict__ out)           // [N, D]
{
    const int lane = threadIdx.x & 63;
    const int wib  = threadIdx.x >> 6;           // wave index in block
    const int wpb  = blockDim.x >> 6;            // waves per block (4)
    const int gw   = blockIdx.x * wpb + wib;     // global wave id
    const int nw   = gridDim.x * wpb;            // total waves

    // Load alpha_w once into registers (same layout as the x loads)
    const v4f* w4 = (const v4f*)alpha_w;
    const v4f w0 = w4[lane];
    const v4f w1 = w4[64 + lane];
    const float bias = alpha_b[0];

    for (int n = gw; n < NROWS; n += nw) {
        v4f x[NVIEWS][2];
        float dot[NVIEWS];
#pragma unroll
        for (int v = 0; v < NVIEWS; ++v) {
            const v4f* xr = (const v4f*)(xs + ((size_t)v * NROWS + n) * DDIM);
            x[v][0] = xr[lane];        // floats [4*lane .. 4*lane+3]
            x[v][1] = xr[64 + lane];   // floats [256+4*lane .. ]
            v4f p = x[v][0] * w0 + x[v][1] * w1;
            dot[v] = p[0] + p[1] + p[2] + p[3];
        }

        // 64-lane butterfly reduction of the 3 partial dots
#pragma unroll
        for (int off = 32; off; off >>= 1) {
#pragma unroll
            for (int v = 0; v < NVIEWS; ++v)
                dot[v] += __shfl_xor(dot[v], off, 64);
        }

        // leaky_relu logits
        float l[NVIEWS];
#pragma unroll
        for (int v = 0; v < NVIEWS; ++v) {
            const float t = dot[v] + bias;
            l[v] = t > 0.0f ? t : NEG_SLOPE * t;
        }

        // softmax over the 3 views (computed redundantly in every lane)
        const float m = fmaxf(fmaxf(l[0], l[1]), l[2]);
        float e[NVIEWS];
        float s = 0.0f;
#pragma unroll
        for (int v = 0; v < NVIEWS; ++v) { e[v] = __expf(l[v] - m); s += e[v]; }
        const float inv = 1.0f / s;
        const float a0 = e[0] * inv, a1 = e[1] * inv, a2 = e[2] * inv;

        // weighted sum straight from registers; store 2 x float4 per lane
        const v4f o0 = a0 * x[0][0] + a1 * x[1][0] + a2 * x[2][0];
        const v4f o1 = a0 * x[0][1] + a1 * x[1][1] + a2 * x[2][1];
        v4f* orow = (v4f*)(out + (size_t)n * DDIM);
        orow[lane]      = o0;
        orow[64 + lane] = o1;
    }
}

extern "C" void kernel_launch(void* const* d_in, const int* in_sizes, int n_in,
                              void* d_out, int out_size, void* d_ws, size_t ws_size,
                              hipStream_t stream) {
    const float* xs      = (const float*)d_in[0];
    const float* alpha_w = (const float*)d_in[1];
    const float* alpha_b = (const float*)d_in[2];
    float* out = (float*)d_out;

    // 2048 blocks x 4 waves = 8192 waves; 16 rows per wave via stride loop
    dim3 grid(2048), block(256);
    hipLaunchKernelGGL(adaptive_fusion_kernel, grid, block, 0, stream,
                       xs, alpha_w, alpha_b, out);
}

// Round 5
// 1068.887 us; speedup vs baseline: 1.0169x; 1.0169x over previous
//
#include <hip/hip_runtime.h>

// Problem constants (from the reference)
#define NVIEWS 3
#define NROWS 131072
#define DDIM 512
#define NEG_SLOPE 0.01f

#define NBLOCKS 2048
#define WAVES_PER_BLOCK 4
#define NWAVES (NBLOCKS * WAVES_PER_BLOCK)       // 8192
#define ROWS_PER_WAVE (NROWS / NWAVES)           // 16
#define ROWS_PER_ITER 2
#define NITER (ROWS_PER_WAVE / ROWS_PER_ITER)    // 8

typedef float v4f __attribute__((ext_vector_type(4)));

__device__ __forceinline__ v4f ntload4(const v4f* p) {
    return __builtin_nontemporal_load(p);
}
__device__ __forceinline__ void ntstore4(v4f* p, v4f v) {
    __builtin_nontemporal_store(v, p);
}

// One 64-lane wave owns 16 CONTIGUOUS rows; 2 rows per iteration:
//   - 12 independent nontemporal float4 loads in flight per iteration
//   - 3 dots/row via per-lane FMA + one 6-step shfl_xor butterfly over 6 partials
//   - leaky_relu + 3-way softmax redundantly per lane (no broadcast)
//   - weighted sum straight from registers, nontemporal float4 stores
__global__ __launch_bounds__(256) void adaptive_fusion_kernel(
    const float* __restrict__ xs,      // [V, N, D]
    const float* __restrict__ alpha_w, // [D]
    const float* __restrict__ alpha_b, // [1]
    float* __restrict__ out)           // [N, D]
{
    const int lane = threadIdx.x & 63;
    const int wave = (blockIdx.x * blockDim.x + threadIdx.x) >> 6;  // 0..NWAVES-1

    // alpha_w once into registers (same layout as x loads); L2-resident
    const v4f* w4 = (const v4f*)alpha_w;
    const v4f w0 = w4[lane];
    const v4f w1 = w4[64 + lane];
    const float bias = alpha_b[0];

    const size_t row0 = (size_t)wave * ROWS_PER_WAVE;
    const float* p0 = xs + row0 * DDIM;                    // view 0
    const float* p1 = p0 + (size_t)NROWS * DDIM;           // view 1
    const float* p2 = p1 + (size_t)NROWS * DDIM;           // view 2
    float* po = out + row0 * DDIM;

#pragma unroll 1
    for (int it = 0; it < NITER; ++it) {
        v4f x[ROWS_PER_ITER][NVIEWS][2];

        // Issue all 12 loads back-to-back (independent, nontemporal)
#pragma unroll
        for (int r = 0; r < ROWS_PER_ITER; ++r) {
            const v4f* b0 = (const v4f*)(p0 + r * DDIM);
            const v4f* b1 = (const v4f*)(p1 + r * DDIM);
            const v4f* b2 = (const v4f*)(p2 + r * DDIM);
            x[r][0][0] = ntload4(b0 + lane);
            x[r][0][1] = ntload4(b0 + 64 + lane);
            x[r][1][0] = ntload4(b1 + lane);
            x[r][1][1] = ntload4(b1 + 64 + lane);
            x[r][2][0] = ntload4(b2 + lane);
            x[r][2][1] = ntload4(b2 + 64 + lane);
        }

        // Per-lane partial dots: 6 values (2 rows x 3 views)
        float d[ROWS_PER_ITER * NVIEWS];
#pragma unroll
        for (int r = 0; r < ROWS_PER_ITER; ++r) {
#pragma unroll
            for (int v = 0; v < NVIEWS; ++v) {
                v4f p = x[r][v][0] * w0 + x[r][v][1] * w1;
                d[r * NVIEWS + v] = p[0] + p[1] + p[2] + p[3];
            }
        }

        // One 64-lane butterfly over all 6 partials
#pragma unroll
        for (int off = 32; off; off >>= 1) {
#pragma unroll
            for (int i = 0; i < ROWS_PER_ITER * NVIEWS; ++i)
                d[i] += __shfl_xor(d[i], off, 64);
        }

        // Softmax over views + weighted sum, per row
#pragma unroll
        for (int r = 0; r < ROWS_PER_ITER; ++r) {
            float l[NVIEWS];
#pragma unroll
            for (int v = 0; v < NVIEWS; ++v) {
                const float t = d[r * NVIEWS + v] + bias;
                l[v] = t > 0.0f ? t : NEG_SLOPE * t;
            }
            const float m = fmaxf(fmaxf(l[0], l[1]), l[2]);
            float e0 = __expf(l[0] - m), e1 = __expf(l[1] - m), e2 = __expf(l[2] - m);
            const float inv = 1.0f / (e0 + e1 + e2);
            const float a0 = e0 * inv, a1 = e1 * inv, a2 = e2 * inv;

            const v4f o0 = a0 * x[r][0][0] + a1 * x[r][1][0] + a2 * x[r][2][0];
            const v4f o1 = a0 * x[r][0][1] + a1 * x[r][1][1] + a2 * x[r][2][1];
            v4f* orow = (v4f*)(po + r * DDIM);
            ntstore4(orow + lane, o0);
            ntstore4(orow + 64 + lane, o1);
        }

        p0 += ROWS_PER_ITER * DDIM;
        p1 += ROWS_PER_ITER * DDIM;
        p2 += ROWS_PER_ITER * DDIM;
        po += ROWS_PER_ITER * DDIM;
    }
}

extern "C" void kernel_launch(void* const* d_in, const int* in_sizes, int n_in,
                              void* d_out, int out_size, void* d_ws, size_t ws_size,
                              hipStream_t stream) {
    const float* xs      = (const float*)d_in[0];
    const float* alpha_w = (const float*)d_in[1];
    const float* alpha_b = (const float*)d_in[2];
    float* out = (float*)d_out;

    dim3 grid(NBLOCKS), block(WAVES_PER_BLOCK * 64);
    hipLaunchKernelGGL(adaptive_fusion_kernel, grid, block, 0, stream,
                       xs, alpha_w, alpha_b, out);
}